// Round 9
// baseline (133.273 us; speedup 1.0000x reference)
//
#include <hip/hip_runtime.h>
#include <math.h>

#define DIM 128
#define NEG_SLOPE 0.01f
#define L2_EPS 1e-12f
#define CAP 32        // bucket slots/node; deg ~ Poisson(6), P(deg>32) ~ 1e-13
#define CSTRIDE 16    // cnt stride in ints: one counter per 64B line

typedef unsigned int uint32;
typedef unsigned short ushort16;

// fp32 -> bf16 round-to-nearest-even
__device__ inline ushort16 f2bf(float f) {
    uint32 u = __float_as_uint(f);
    u += 0x7fffu + ((u >> 16) & 1u);
    return (ushort16)(u >> 16);
}

__device__ inline float bf_lo(uint32 v) { return __uint_as_float((v & 0xffffu) << 16); }
__device__ inline float bf_hi(uint32 v) { return __uint_as_float(v & 0xffff0000u); }

__device__ inline void accum8(uint4 v, float w, float* acc) {
    acc[0] = fmaf(bf_lo(v.x), w, acc[0]);
    acc[1] = fmaf(bf_hi(v.x), w, acc[1]);
    acc[2] = fmaf(bf_lo(v.y), w, acc[2]);
    acc[3] = fmaf(bf_hi(v.y), w, acc[3]);
    acc[4] = fmaf(bf_lo(v.z), w, acc[4]);
    acc[5] = fmaf(bf_hi(v.z), w, acc[5]);
    acc[6] = fmaf(bf_lo(v.w), w, acc[6]);
    acc[7] = fmaf(bf_hi(v.w), w, acc[7]);
}

// ---------- Fused: row L2-normalize (bf16 x -> ws) + direct bucket fill ----------
// Norm: 8 lanes/row, 4 consecutive float4 loads per lane, 8 rows/wave.
// Fill: 2 edges/thread; doubled list src[k]=ei[k], dst[k]=ei[(k+E) mod 2E];
// pos = atomicAdd(cnt[dst*CSTRIDE]) assigns the slot directly (stride CAP).
// cnt is padded to one counter per 64B line to kill cross-XCD line ping-pong.
__global__ __launch_bounds__(256) void norm_fill_kernel(
    const float* __restrict__ in, ushort16* __restrict__ xbf,
    const int* __restrict__ ei, const float* __restrict__ w,
    int* __restrict__ cnt, int2* __restrict__ buckets,
    int n_rows, int E, int norm_blocks) {
    if ((int)blockIdx.x < norm_blocks) {
        int gid = blockIdx.x * 256 + threadIdx.x;
        int row = gid >> 3;
        int lane = gid & 7;
        if (row >= n_rows) return;
        const float4* rp = reinterpret_cast<const float4*>(in + (size_t)row * DIM) + lane * 4;
        float4 a = rp[0];
        float4 b = rp[1];
        float4 c = rp[2];
        float4 d = rp[3];
        float ss = a.x * a.x + a.y * a.y + a.z * a.z + a.w * a.w
                 + b.x * b.x + b.y * b.y + b.z * b.z + b.w * b.w
                 + c.x * c.x + c.y * c.y + c.z * c.z + c.w * c.w
                 + d.x * d.x + d.y * d.y + d.z * d.z + d.w * d.w;
        #pragma unroll
        for (int m = 1; m < 8; m <<= 1) ss += __shfl_xor(ss, m, 8);
        float scale = 1.0f / fmaxf(sqrtf(ss), L2_EPS);
        uint4 p0, p1;
        p0.x = (uint32)f2bf(a.x * scale) | ((uint32)f2bf(a.y * scale) << 16);
        p0.y = (uint32)f2bf(a.z * scale) | ((uint32)f2bf(a.w * scale) << 16);
        p0.z = (uint32)f2bf(b.x * scale) | ((uint32)f2bf(b.y * scale) << 16);
        p0.w = (uint32)f2bf(b.z * scale) | ((uint32)f2bf(b.w * scale) << 16);
        p1.x = (uint32)f2bf(c.x * scale) | ((uint32)f2bf(c.y * scale) << 16);
        p1.y = (uint32)f2bf(c.z * scale) | ((uint32)f2bf(c.w * scale) << 16);
        p1.z = (uint32)f2bf(d.x * scale) | ((uint32)f2bf(d.y * scale) << 16);
        p1.w = (uint32)f2bf(d.z * scale) | ((uint32)f2bf(d.w * scale) << 16);
        uint4* q = reinterpret_cast<uint4*>(xbf + (size_t)row * DIM + lane * 16);
        q[0] = p0;
        q[1] = p1;
    } else {
        int t = ((int)blockIdx.x - norm_blocks) * 256 + threadIdx.x;
        int e0 = t * 2;
        if (e0 >= 2 * E) return;
        int2 srcs = *reinterpret_cast<const int2*>(ei + e0);          // ei[e0], ei[e0+1]
        int d0 = (e0 < E) ? ei[e0 + E] : ei[e0 - E];
        int d1 = (e0 + 1 < E) ? ei[e0 + 1 + E] : ei[e0 + 1 - E];
        float2 we = *reinterpret_cast<const float2*>(w + e0);
        int pos0 = atomicAdd(&cnt[(size_t)d0 * CSTRIDE], 1);
        int pos1 = atomicAdd(&cnt[(size_t)d1 * CSTRIDE], 1);
        if (pos0 < CAP)
            buckets[(size_t)d0 * CAP + pos0] = make_int2(srcs.x, __float_as_int(we.x));
        if (pos1 < CAP)
            buckets[(size_t)d1 * CAP + pos1] = make_int2(srcs.y, __float_as_int(we.y));
    }
}

// ---------- Node-parallel gather-reduce conv ----------
// 16 lanes per row: one dwordx4 per lane covers the full 256B bf16 row in one
// fully-coalesced instruction. 8 bucket entries prefetched per batch, all
// gathers issued concurrently (4 rows/wave -> up to 32 gathers in flight).
// Batches (k=0,8,16,24) stay exactly inside the CAP=32 slot row.
// MODE 0: x1_bf[row] = bf16(leaky(acc / max(deg,1)))
// MODE 1: out[row] = x_bf[row] + x1_bf[row] + leaky(acc / max(deg,1))
template <int MODE>
__global__ __launch_bounds__(256) void conv_kernel(
    const ushort16* __restrict__ xin_bf, const int* __restrict__ cnt,
    const int2* __restrict__ buckets, ushort16* __restrict__ x1_bf,
    const ushort16* __restrict__ x_bf, float* __restrict__ out, int n_rows) {
    int row = (int)((blockIdx.x * 256 + threadIdx.x) >> 4);
    int lane = threadIdx.x & 15;
    if (row >= n_rows) return;
    int deg = cnt[(size_t)row * CSTRIDE];
    deg = deg < CAP ? deg : CAP;
    const int2* bp = buckets + (size_t)row * CAP;
    float acc[8];
    #pragma unroll
    for (int i = 0; i < 8; ++i) acc[i] = 0.f;

    int k = 0;
    while (k < deg) {
        int nb = deg - k;            // remaining edges (uniform per 16-lane group)
        int2 p[8];
        #pragma unroll
        for (int j = 0; j < 8; ++j) p[j] = bp[k + j];  // within CAP row: safe
        uint4 v[8];
        #pragma unroll
        for (int j = 0; j < 8; ++j)
            if (j < nb)
                v[j] = *reinterpret_cast<const uint4*>(
                    xin_bf + (size_t)p[j].x * DIM + lane * 8);
        #pragma unroll
        for (int j = 0; j < 8; ++j)
            if (j < nb) accum8(v[j], __int_as_float(p[j].y), acc);
        k += 8;
    }

    float invc = 1.0f / fmaxf((float)deg, 1.0f);
    #pragma unroll
    for (int i = 0; i < 8; ++i) {
        acc[i] *= invc;
        acc[i] = acc[i] > 0.f ? acc[i] : NEG_SLOPE * acc[i];
    }
    size_t off = (size_t)row * DIM + lane * 8;
    if (MODE == 0) {
        uint4 pk;
        pk.x = (uint32)f2bf(acc[0]) | ((uint32)f2bf(acc[1]) << 16);
        pk.y = (uint32)f2bf(acc[2]) | ((uint32)f2bf(acc[3]) << 16);
        pk.z = (uint32)f2bf(acc[4]) | ((uint32)f2bf(acc[5]) << 16);
        pk.w = (uint32)f2bf(acc[6]) | ((uint32)f2bf(acc[7]) << 16);
        *reinterpret_cast<uint4*>(x1_bf + off) = pk;
    } else {
        uint4 xa = *reinterpret_cast<const uint4*>(x_bf + off);
        uint4 ya = *reinterpret_cast<const uint4*>(x1_bf + off);
        float4 o0, o1;
        o0.x = bf_lo(xa.x) + bf_lo(ya.x) + acc[0];
        o0.y = bf_hi(xa.x) + bf_hi(ya.x) + acc[1];
        o0.z = bf_lo(xa.y) + bf_lo(ya.y) + acc[2];
        o0.w = bf_hi(xa.y) + bf_hi(ya.y) + acc[3];
        o1.x = bf_lo(xa.z) + bf_lo(ya.z) + acc[4];
        o1.y = bf_hi(xa.z) + bf_hi(ya.z) + acc[5];
        o1.z = bf_lo(xa.w) + bf_lo(ya.w) + acc[6];
        o1.w = bf_hi(xa.w) + bf_hi(ya.w) + acc[7];
        float4* op = reinterpret_cast<float4*>(out + off);
        op[0] = o0;
        op[1] = o1;
    }
}

extern "C" void kernel_launch(void* const* d_in, const int* in_sizes, int n_in,
                              void* d_out, int out_size, void* d_ws, size_t ws_size,
                              hipStream_t stream) {
    const float* id_emb = (const float*)d_in[0];
    const int* ei = (const int*)d_in[1];
    const float* w = (const float*)d_in[2];
    float* out = (float*)d_out;

    const int N = in_sizes[0] / DIM;      // 100000
    const int E = in_sizes[1] / 2;        // 300000
    const size_t ND = (size_t)N * DIM;

    // workspace layout
    ushort16* x_bf = (ushort16*)d_ws;               // ND bf16            (25.6 MB)
    ushort16* x1_bf = x_bf + ND;                    // ND bf16            (25.6 MB)
    int* cnt = (int*)(x1_bf + ND);                  // N*CSTRIDE ints     (6.4 MB)
    int2* buckets = (int2*)(cnt + (size_t)N * CSTRIDE);  // N*CAP int2    (25.6 MB)

    hipMemsetAsync(cnt, 0, (size_t)N * CSTRIDE * sizeof(int), stream);

    // fused: x = normalize(id_emb) -> x_bf (bf16); direct bucket fill
    {
        int nb = (N * 8 + 255) / 256;
        int fb = (E + 255) / 256;   // 2 edges per thread
        norm_fill_kernel<<<nb + fb, 256, 0, stream>>>(
            id_emb, x_bf, ei, w, cnt, buckets, N, E, nb);
    }

    // conv1: gather x_bf -> x1_bf
    conv_kernel<0><<<(N * 16 + 255) / 256, 256, 0, stream>>>(
        x_bf, cnt, buckets, x1_bf, nullptr, nullptr, N);
    // conv2 + final fusion: out = x + x1 + leaky(mean)
    conv_kernel<1><<<(N * 16 + 255) / 256, 256, 0, stream>>>(
        x1_bf, cnt, buckets, x1_bf, x_bf, out, N);
}

// Round 10
// 123.644 us; speedup vs baseline: 1.0779x; 1.0779x over previous
//
#include <hip/hip_runtime.h>
#include <math.h>

#define DIM 128
#define NEG_SLOPE 0.01f
#define L2_EPS 1e-12f
#define CAP 32   // bucket slots/node; deg ~ Poisson(6), P(deg>32) ~ 1e-13

typedef unsigned int uint32;
typedef unsigned short ushort16;

// fp32 -> bf16 round-to-nearest-even
__device__ inline ushort16 f2bf(float f) {
    uint32 u = __float_as_uint(f);
    u += 0x7fffu + ((u >> 16) & 1u);
    return (ushort16)(u >> 16);
}

__device__ inline float bf_lo(uint32 v) { return __uint_as_float((v & 0xffffu) << 16); }
__device__ inline float bf_hi(uint32 v) { return __uint_as_float(v & 0xffff0000u); }

__device__ inline void accum8(uint4 v, float w, float* acc) {
    acc[0] = fmaf(bf_lo(v.x), w, acc[0]);
    acc[1] = fmaf(bf_hi(v.x), w, acc[1]);
    acc[2] = fmaf(bf_lo(v.y), w, acc[2]);
    acc[3] = fmaf(bf_hi(v.y), w, acc[3]);
    acc[4] = fmaf(bf_lo(v.z), w, acc[4]);
    acc[5] = fmaf(bf_hi(v.z), w, acc[5]);
    acc[6] = fmaf(bf_lo(v.w), w, acc[6]);
    acc[7] = fmaf(bf_hi(v.w), w, acc[7]);
}

// ---------- Fused: row L2-normalize (bf16 x -> ws) + direct bucket fill ----------
// Norm: 8 lanes/row, 4 consecutive float4 loads per lane, 8 rows/wave.
// Fill: 1 edge/thread; doubled list src[k]=ei[k], dst[k]=ei[(k+E) mod 2E].
// Byte-packed counters: 4 per int -> 64 counters per 64B line (memory-side
// atomics merge better with fewer distinct lines; r9 showed padding = worse).
__global__ __launch_bounds__(256) void norm_fill_kernel(
    const float* __restrict__ in, ushort16* __restrict__ xbf,
    const int* __restrict__ ei, const float* __restrict__ w,
    uint32* __restrict__ cnt, int2* __restrict__ buckets,
    int n_rows, int E, int norm_blocks) {
    if ((int)blockIdx.x < norm_blocks) {
        int gid = blockIdx.x * 256 + threadIdx.x;
        int row = gid >> 3;
        int lane = gid & 7;
        if (row >= n_rows) return;
        const float4* rp = reinterpret_cast<const float4*>(in + (size_t)row * DIM) + lane * 4;
        float4 a = rp[0];
        float4 b = rp[1];
        float4 c = rp[2];
        float4 d = rp[3];
        float ss = a.x * a.x + a.y * a.y + a.z * a.z + a.w * a.w
                 + b.x * b.x + b.y * b.y + b.z * b.z + b.w * b.w
                 + c.x * c.x + c.y * c.y + c.z * c.z + c.w * c.w
                 + d.x * d.x + d.y * d.y + d.z * d.z + d.w * d.w;
        #pragma unroll
        for (int m = 1; m < 8; m <<= 1) ss += __shfl_xor(ss, m, 8);
        float scale = 1.0f / fmaxf(sqrtf(ss), L2_EPS);
        uint4 p0, p1;
        p0.x = (uint32)f2bf(a.x * scale) | ((uint32)f2bf(a.y * scale) << 16);
        p0.y = (uint32)f2bf(a.z * scale) | ((uint32)f2bf(a.w * scale) << 16);
        p0.z = (uint32)f2bf(b.x * scale) | ((uint32)f2bf(b.y * scale) << 16);
        p0.w = (uint32)f2bf(b.z * scale) | ((uint32)f2bf(b.w * scale) << 16);
        p1.x = (uint32)f2bf(c.x * scale) | ((uint32)f2bf(c.y * scale) << 16);
        p1.y = (uint32)f2bf(c.z * scale) | ((uint32)f2bf(c.w * scale) << 16);
        p1.z = (uint32)f2bf(d.x * scale) | ((uint32)f2bf(d.y * scale) << 16);
        p1.w = (uint32)f2bf(d.z * scale) | ((uint32)f2bf(d.w * scale) << 16);
        uint4* q = reinterpret_cast<uint4*>(xbf + (size_t)row * DIM + lane * 16);
        q[0] = p0;
        q[1] = p1;
    } else {
        int e = ((int)blockIdx.x - norm_blocks) * 256 + threadIdx.x;
        if (e >= 2 * E) return;
        int src = ei[e];
        int dst = (e < E) ? ei[e + E] : ei[e - E];
        int sh = 8 * (dst & 3);
        uint32 old = atomicAdd(&cnt[dst >> 2], 1u << sh);
        int pos = (int)((old >> sh) & 0xffu);
        if (pos < CAP)
            buckets[(size_t)dst * CAP + pos] = make_int2(src, __float_as_int(w[e]));
    }
}

// ---------- Node-parallel gather-reduce conv ----------
// 16 lanes per row: one dwordx4 per lane covers the full 256B bf16 row in one
// fully-coalesced instruction. 8 bucket entries prefetched per batch, all
// gathers issued concurrently (4 rows/wave -> up to 32 gathers in flight).
// Batches (k=0,8,16,24) stay exactly inside the CAP=32 slot row.
// MODE 0: x1_bf[row] = bf16(leaky(acc / max(deg,1)))
// MODE 1: out[row] = x_bf[row] + x1_bf[row] + leaky(acc / max(deg,1))
template <int MODE>
__global__ __launch_bounds__(256) void conv_kernel(
    const ushort16* __restrict__ xin_bf, const uint32* __restrict__ cnt,
    const int2* __restrict__ buckets, ushort16* __restrict__ x1_bf,
    const ushort16* __restrict__ x_bf, float* __restrict__ out, int n_rows) {
    int row = (int)((blockIdx.x * 256 + threadIdx.x) >> 4);
    int lane = threadIdx.x & 15;
    if (row >= n_rows) return;
    int deg = (int)((cnt[row >> 2] >> (8 * (row & 3))) & 0xffu);
    deg = deg < CAP ? deg : CAP;
    const int2* bp = buckets + (size_t)row * CAP;
    float acc[8];
    #pragma unroll
    for (int i = 0; i < 8; ++i) acc[i] = 0.f;

    int k = 0;
    while (k < deg) {
        int nb = deg - k;            // remaining edges (uniform per 16-lane group)
        int2 p[8];
        #pragma unroll
        for (int j = 0; j < 8; ++j) p[j] = bp[k + j];  // within CAP row: safe
        uint4 v[8];
        #pragma unroll
        for (int j = 0; j < 8; ++j)
            if (j < nb)
                v[j] = *reinterpret_cast<const uint4*>(
                    xin_bf + (size_t)p[j].x * DIM + lane * 8);
        #pragma unroll
        for (int j = 0; j < 8; ++j)
            if (j < nb) accum8(v[j], __int_as_float(p[j].y), acc);
        k += 8;
    }

    float invc = 1.0f / fmaxf((float)deg, 1.0f);
    #pragma unroll
    for (int i = 0; i < 8; ++i) {
        acc[i] *= invc;
        acc[i] = acc[i] > 0.f ? acc[i] : NEG_SLOPE * acc[i];
    }
    size_t off = (size_t)row * DIM + lane * 8;
    if (MODE == 0) {
        uint4 pk;
        pk.x = (uint32)f2bf(acc[0]) | ((uint32)f2bf(acc[1]) << 16);
        pk.y = (uint32)f2bf(acc[2]) | ((uint32)f2bf(acc[3]) << 16);
        pk.z = (uint32)f2bf(acc[4]) | ((uint32)f2bf(acc[5]) << 16);
        pk.w = (uint32)f2bf(acc[6]) | ((uint32)f2bf(acc[7]) << 16);
        *reinterpret_cast<uint4*>(x1_bf + off) = pk;
    } else {
        uint4 xa = *reinterpret_cast<const uint4*>(x_bf + off);
        uint4 ya = *reinterpret_cast<const uint4*>(x1_bf + off);
        float4 o0, o1;
        o0.x = bf_lo(xa.x) + bf_lo(ya.x) + acc[0];
        o0.y = bf_hi(xa.x) + bf_hi(ya.x) + acc[1];
        o0.z = bf_lo(xa.y) + bf_lo(ya.y) + acc[2];
        o0.w = bf_hi(xa.y) + bf_hi(ya.y) + acc[3];
        o1.x = bf_lo(xa.z) + bf_lo(ya.z) + acc[4];
        o1.y = bf_hi(xa.z) + bf_hi(ya.z) + acc[5];
        o1.z = bf_lo(xa.w) + bf_lo(ya.w) + acc[6];
        o1.w = bf_hi(xa.w) + bf_hi(ya.w) + acc[7];
        float4* op = reinterpret_cast<float4*>(out + off);
        op[0] = o0;
        op[1] = o1;
    }
}

extern "C" void kernel_launch(void* const* d_in, const int* in_sizes, int n_in,
                              void* d_out, int out_size, void* d_ws, size_t ws_size,
                              hipStream_t stream) {
    const float* id_emb = (const float*)d_in[0];
    const int* ei = (const int*)d_in[1];
    const float* w = (const float*)d_in[2];
    float* out = (float*)d_out;

    const int N = in_sizes[0] / DIM;      // 100000
    const int E = in_sizes[1] / 2;        // 300000
    const size_t ND = (size_t)N * DIM;
    const int cnt_ints = ((N + 3) / 4 + 3) & ~3;   // byte counters, 4/int, padded

    // workspace layout
    ushort16* x_bf = (ushort16*)d_ws;               // ND bf16        (25.6 MB)
    ushort16* x1_bf = x_bf + ND;                    // ND bf16        (25.6 MB)
    uint32* cnt = (uint32*)(x1_bf + ND);            // cnt_ints ints  (100 KB)
    int2* buckets = (int2*)(cnt + cnt_ints);        // N*CAP int2     (25.6 MB)

    hipMemsetAsync(cnt, 0, (size_t)cnt_ints * sizeof(uint32), stream);

    // fused: x = normalize(id_emb) -> x_bf (bf16); direct bucket fill
    {
        int nb = (N * 8 + 255) / 256;
        int fb = (2 * E + 255) / 256;
        norm_fill_kernel<<<nb + fb, 256, 0, stream>>>(
            id_emb, x_bf, ei, w, cnt, buckets, N, E, nb);
    }

    // conv1: gather x_bf -> x1_bf
    conv_kernel<0><<<(N * 16 + 255) / 256, 256, 0, stream>>>(
        x_bf, cnt, buckets, x1_bf, nullptr, nullptr, N);
    // conv2 + final fusion: out = x + x1 + leaky(mean)
    conv_kernel<1><<<(N * 16 + 255) / 256, 256, 0, stream>>>(
        x1_bf, cnt, buckets, x1_bf, x_bf, out, N);
}

// Round 13
// 120.996 us; speedup vs baseline: 1.1015x; 1.0219x over previous
//
#include <hip/hip_runtime.h>
#include <math.h>

#define DIM 128
#define NEG_SLOPE 0.01f
#define L2_EPS 1e-12f
#define CAP 32   // bucket slots/node; deg ~ Poisson(6), P(deg>32) ~ 1e-13

typedef unsigned int uint32;
typedef unsigned short ushort16;

// fp32 -> bf16 round-to-nearest-even
__device__ inline ushort16 f2bf(float f) {
    uint32 u = __float_as_uint(f);
    u += 0x7fffu + ((u >> 16) & 1u);
    return (ushort16)(u >> 16);
}

__device__ inline float bf_lo(uint32 v) { return __uint_as_float((v & 0xffffu) << 16); }
__device__ inline float bf_hi(uint32 v) { return __uint_as_float(v & 0xffff0000u); }

__device__ inline void accum8(uint4 v, float w, float* acc) {
    acc[0] = fmaf(bf_lo(v.x), w, acc[0]);
    acc[1] = fmaf(bf_hi(v.x), w, acc[1]);
    acc[2] = fmaf(bf_lo(v.y), w, acc[2]);
    acc[3] = fmaf(bf_hi(v.y), w, acc[3]);
    acc[4] = fmaf(bf_lo(v.z), w, acc[4]);
    acc[5] = fmaf(bf_hi(v.z), w, acc[5]);
    acc[6] = fmaf(bf_lo(v.w), w, acc[6]);
    acc[7] = fmaf(bf_hi(v.w), w, acc[7]);
}

// ---------- Fused: row L2-normalize (bf16 x -> ws) + direct bucket fill ----------
// Norm: 8 lanes/row, 4 consecutive float4 loads per lane, 8 rows/wave.
// Fill: 1 edge/thread; doubled list src[k]=ei[k], dst[k]=ei[(k+E) mod 2E].
// One int32 counter per node (best of three measured layouts: padded and
// byte-packed both regress); pos = atomicAdd assigns the slot directly.
__global__ __launch_bounds__(256) void norm_fill_kernel(
    const float* __restrict__ in, ushort16* __restrict__ xbf,
    const int* __restrict__ ei, const float* __restrict__ w,
    int* __restrict__ cnt, int2* __restrict__ buckets,
    int n_rows, int E, int norm_blocks) {
    if ((int)blockIdx.x < norm_blocks) {
        int gid = blockIdx.x * 256 + threadIdx.x;
        int row = gid >> 3;
        int lane = gid & 7;
        if (row >= n_rows) return;
        const float4* rp = reinterpret_cast<const float4*>(in + (size_t)row * DIM) + lane * 4;
        float4 a = rp[0];
        float4 b = rp[1];
        float4 c = rp[2];
        float4 d = rp[3];
        float ss = a.x * a.x + a.y * a.y + a.z * a.z + a.w * a.w
                 + b.x * b.x + b.y * b.y + b.z * b.z + b.w * b.w
                 + c.x * c.x + c.y * c.y + c.z * c.z + c.w * c.w
                 + d.x * d.x + d.y * d.y + d.z * d.z + d.w * d.w;
        #pragma unroll
        for (int m = 1; m < 8; m <<= 1) ss += __shfl_xor(ss, m, 8);
        float scale = 1.0f / fmaxf(sqrtf(ss), L2_EPS);
        uint4 p0, p1;
        p0.x = (uint32)f2bf(a.x * scale) | ((uint32)f2bf(a.y * scale) << 16);
        p0.y = (uint32)f2bf(a.z * scale) | ((uint32)f2bf(a.w * scale) << 16);
        p0.z = (uint32)f2bf(b.x * scale) | ((uint32)f2bf(b.y * scale) << 16);
        p0.w = (uint32)f2bf(b.z * scale) | ((uint32)f2bf(b.w * scale) << 16);
        p1.x = (uint32)f2bf(c.x * scale) | ((uint32)f2bf(c.y * scale) << 16);
        p1.y = (uint32)f2bf(c.z * scale) | ((uint32)f2bf(c.w * scale) << 16);
        p1.z = (uint32)f2bf(d.x * scale) | ((uint32)f2bf(d.y * scale) << 16);
        p1.w = (uint32)f2bf(d.z * scale) | ((uint32)f2bf(d.w * scale) << 16);
        uint4* q = reinterpret_cast<uint4*>(xbf + (size_t)row * DIM + lane * 16);
        q[0] = p0;
        q[1] = p1;
    } else {
        int e = ((int)blockIdx.x - norm_blocks) * 256 + threadIdx.x;
        if (e >= 2 * E) return;
        int src = ei[e];
        int dst = (e < E) ? ei[e + E] : ei[e - E];
        int pos = atomicAdd(&cnt[dst], 1);
        if (pos < CAP)
            buckets[(size_t)dst * CAP + pos] = make_int2(src, __float_as_int(w[e]));
    }
}

// ---------- Node-parallel gather-reduce conv ----------
// 16 lanes per row: one dwordx4 per lane covers the full 256B bf16 row in one
// fully-coalesced instruction. 8 bucket entries prefetched per batch, all
// gathers issued concurrently (4 rows/wave -> up to 32 gathers in flight).
// Batches (k=0,8,16,24) stay exactly inside the CAP=32 slot row.
// MODE 0: x1_bf[row] = bf16(leaky(acc / max(deg,1)))
// MODE 1: out[row] = x_bf[row] + x1_bf[row] + leaky(acc / max(deg,1))
template <int MODE>
__global__ __launch_bounds__(256) void conv_kernel(
    const ushort16* __restrict__ xin_bf, const int* __restrict__ cnt,
    const int2* __restrict__ buckets, ushort16* __restrict__ x1_bf,
    const ushort16* __restrict__ x_bf, float* __restrict__ out, int n_rows) {
    int row = (int)((blockIdx.x * 256 + threadIdx.x) >> 4);
    int lane = threadIdx.x & 15;
    if (row >= n_rows) return;
    int deg = cnt[row];
    deg = deg < CAP ? deg : CAP;
    const int2* bp = buckets + (size_t)row * CAP;
    float acc[8];
    #pragma unroll
    for (int i = 0; i < 8; ++i) acc[i] = 0.f;

    int k = 0;
    while (k < deg) {
        int nb = deg - k;            // remaining edges (uniform per 16-lane group)
        int2 p[8];
        #pragma unroll
        for (int j = 0; j < 8; ++j) p[j] = bp[k + j];  // within CAP row: safe
        uint4 v[8];
        #pragma unroll
        for (int j = 0; j < 8; ++j)
            if (j < nb)
                v[j] = *reinterpret_cast<const uint4*>(
                    xin_bf + (size_t)p[j].x * DIM + lane * 8);
        #pragma unroll
        for (int j = 0; j < 8; ++j)
            if (j < nb) accum8(v[j], __int_as_float(p[j].y), acc);
        k += 8;
    }

    float invc = 1.0f / fmaxf((float)deg, 1.0f);
    #pragma unroll
    for (int i = 0; i < 8; ++i) {
        acc[i] *= invc;
        acc[i] = acc[i] > 0.f ? acc[i] : NEG_SLOPE * acc[i];
    }
    size_t off = (size_t)row * DIM + lane * 8;
    if (MODE == 0) {
        uint4 pk;
        pk.x = (uint32)f2bf(acc[0]) | ((uint32)f2bf(acc[1]) << 16);
        pk.y = (uint32)f2bf(acc[2]) | ((uint32)f2bf(acc[3]) << 16);
        pk.z = (uint32)f2bf(acc[4]) | ((uint32)f2bf(acc[5]) << 16);
        pk.w = (uint32)f2bf(acc[6]) | ((uint32)f2bf(acc[7]) << 16);
        *reinterpret_cast<uint4*>(x1_bf + off) = pk;
    } else {
        uint4 xa = *reinterpret_cast<const uint4*>(x_bf + off);
        uint4 ya = *reinterpret_cast<const uint4*>(x1_bf + off);
        float4 o0, o1;
        o0.x = bf_lo(xa.x) + bf_lo(ya.x) + acc[0];
        o0.y = bf_hi(xa.x) + bf_hi(ya.x) + acc[1];
        o0.z = bf_lo(xa.y) + bf_lo(ya.y) + acc[2];
        o0.w = bf_hi(xa.y) + bf_hi(ya.y) + acc[3];
        o1.x = bf_lo(xa.z) + bf_lo(ya.z) + acc[4];
        o1.y = bf_hi(xa.z) + bf_hi(ya.z) + acc[5];
        o1.z = bf_lo(xa.w) + bf_lo(ya.w) + acc[6];
        o1.w = bf_hi(xa.w) + bf_hi(ya.w) + acc[7];
        float4* op = reinterpret_cast<float4*>(out + off);
        op[0] = o0;
        op[1] = o1;
    }
}

extern "C" void kernel_launch(void* const* d_in, const int* in_sizes, int n_in,
                              void* d_out, int out_size, void* d_ws, size_t ws_size,
                              hipStream_t stream) {
    const float* id_emb = (const float*)d_in[0];
    const int* ei = (const int*)d_in[1];
    const float* w = (const float*)d_in[2];
    float* out = (float*)d_out;

    const int N = in_sizes[0] / DIM;      // 100000
    const int E = in_sizes[1] / 2;        // 300000
    const size_t ND = (size_t)N * DIM;

    // workspace layout
    ushort16* x_bf = (ushort16*)d_ws;               // ND bf16        (25.6 MB)
    ushort16* x1_bf = x_bf + ND;                    // ND bf16        (25.6 MB)
    int* cnt = (int*)(x1_bf + ND);                  // N ints         (0.4 MB)
    int2* buckets = (int2*)(cnt + N);               // N*CAP int2     (25.6 MB)

    hipMemsetAsync(cnt, 0, (size_t)N * sizeof(int), stream);

    // fused: x = normalize(id_emb) -> x_bf (bf16); direct bucket fill
    {
        int nb = (N * 8 + 255) / 256;
        int fb = (2 * E + 255) / 256;
        norm_fill_kernel<<<nb + fb, 256, 0, stream>>>(
            id_emb, x_bf, ei, w, cnt, buckets, N, E, nb);
    }

    // conv1: gather x_bf -> x1_bf
    conv_kernel<0><<<(N * 16 + 255) / 256, 256, 0, stream>>>(
        x_bf, cnt, buckets, x1_bf, nullptr, nullptr, N);
    // conv2 + final fusion: out = x + x1 + leaky(mean)
    conv_kernel<1><<<(N * 16 + 255) / 256, 256, 0, stream>>>(
        x1_bf, cnt, buckets, x1_bf, x_bf, out, N);
}

// Round 14
// 117.075 us; speedup vs baseline: 1.1384x; 1.0335x over previous
//
#include <hip/hip_runtime.h>
#include <math.h>

#define DIM 128
#define NEG_SLOPE 0.01f
#define L2_EPS 1e-12f
#define CAP 32   // bucket slots/node; deg ~ Poisson(6), P(deg>32) ~ 1e-13

typedef unsigned int uint32;
typedef unsigned short ushort16;

// fp32 -> bf16 round-to-nearest-even
__device__ inline ushort16 f2bf(float f) {
    uint32 u = __float_as_uint(f);
    u += 0x7fffu + ((u >> 16) & 1u);
    return (ushort16)(u >> 16);
}

__device__ inline float bf_lo(uint32 v) { return __uint_as_float((v & 0xffffu) << 16); }
__device__ inline float bf_hi(uint32 v) { return __uint_as_float(v & 0xffff0000u); }

__device__ inline void accum8(uint4 v, float w, float* acc) {
    acc[0] = fmaf(bf_lo(v.x), w, acc[0]);
    acc[1] = fmaf(bf_hi(v.x), w, acc[1]);
    acc[2] = fmaf(bf_lo(v.y), w, acc[2]);
    acc[3] = fmaf(bf_hi(v.y), w, acc[3]);
    acc[4] = fmaf(bf_lo(v.z), w, acc[4]);
    acc[5] = fmaf(bf_hi(v.z), w, acc[5]);
    acc[6] = fmaf(bf_lo(v.w), w, acc[6]);
    acc[7] = fmaf(bf_hi(v.w), w, acc[7]);
}

// ---------- Fused: direct bucket fill + row L2-normalize (bf16 x -> ws) ----------
// FILL BLOCKS FIRST (low blockIdx): fill threads have the longest latency tail
// (atomic round-trip -> dependent scattered store); dispatching them before the
// norm blocks hides that tail under the norm's bandwidth phase.
// Fill: 1 edge/thread; doubled list src[k]=ei[k], dst[k]=ei[(k+E) mod 2E];
// one int32 counter per node (best of three measured layouts);
// pos = atomicAdd assigns the bucket slot directly.
// Norm: 8 lanes/row, 4 consecutive float4 loads per lane, 8 rows/wave.
__global__ __launch_bounds__(256) void norm_fill_kernel(
    const float* __restrict__ in, ushort16* __restrict__ xbf,
    const int* __restrict__ ei, const float* __restrict__ w,
    int* __restrict__ cnt, int2* __restrict__ buckets,
    int n_rows, int E, int fill_blocks) {
    if ((int)blockIdx.x < fill_blocks) {
        int e = (int)blockIdx.x * 256 + threadIdx.x;
        if (e >= 2 * E) return;
        int src = ei[e];
        int dst = (e < E) ? ei[e + E] : ei[e - E];
        int pos = atomicAdd(&cnt[dst], 1);
        if (pos < CAP)
            buckets[(size_t)dst * CAP + pos] = make_int2(src, __float_as_int(w[e]));
    } else {
        int gid = ((int)blockIdx.x - fill_blocks) * 256 + threadIdx.x;
        int row = gid >> 3;
        int lane = gid & 7;
        if (row >= n_rows) return;
        const float4* rp = reinterpret_cast<const float4*>(in + (size_t)row * DIM) + lane * 4;
        float4 a = rp[0];
        float4 b = rp[1];
        float4 c = rp[2];
        float4 d = rp[3];
        float ss = a.x * a.x + a.y * a.y + a.z * a.z + a.w * a.w
                 + b.x * b.x + b.y * b.y + b.z * b.z + b.w * b.w
                 + c.x * c.x + c.y * c.y + c.z * c.z + c.w * c.w
                 + d.x * d.x + d.y * d.y + d.z * d.z + d.w * d.w;
        #pragma unroll
        for (int m = 1; m < 8; m <<= 1) ss += __shfl_xor(ss, m, 8);
        float scale = 1.0f / fmaxf(sqrtf(ss), L2_EPS);
        uint4 p0, p1;
        p0.x = (uint32)f2bf(a.x * scale) | ((uint32)f2bf(a.y * scale) << 16);
        p0.y = (uint32)f2bf(a.z * scale) | ((uint32)f2bf(a.w * scale) << 16);
        p0.z = (uint32)f2bf(b.x * scale) | ((uint32)f2bf(b.y * scale) << 16);
        p0.w = (uint32)f2bf(b.z * scale) | ((uint32)f2bf(b.w * scale) << 16);
        p1.x = (uint32)f2bf(c.x * scale) | ((uint32)f2bf(c.y * scale) << 16);
        p1.y = (uint32)f2bf(c.z * scale) | ((uint32)f2bf(c.w * scale) << 16);
        p1.z = (uint32)f2bf(d.x * scale) | ((uint32)f2bf(d.y * scale) << 16);
        p1.w = (uint32)f2bf(d.z * scale) | ((uint32)f2bf(d.w * scale) << 16);
        uint4* q = reinterpret_cast<uint4*>(xbf + (size_t)row * DIM + lane * 16);
        q[0] = p0;
        q[1] = p1;
    }
}

// ---------- Node-parallel gather-reduce conv ----------
// 16 lanes per row: one dwordx4 per lane covers the full 256B bf16 row in one
// fully-coalesced instruction. 8 bucket entries prefetched per batch, all
// gathers issued concurrently (4 rows/wave -> up to 32 gathers in flight).
// Batches (k=0,8,16,24) stay exactly inside the CAP=32 slot row.
// MODE 0: x1_bf[row] = bf16(leaky(acc / max(deg,1)))
// MODE 1: out[row] = x_bf[row] + x1_bf[row] + leaky(acc / max(deg,1))
template <int MODE>
__global__ __launch_bounds__(256) void conv_kernel(
    const ushort16* __restrict__ xin_bf, const int* __restrict__ cnt,
    const int2* __restrict__ buckets, ushort16* __restrict__ x1_bf,
    const ushort16* __restrict__ x_bf, float* __restrict__ out, int n_rows) {
    int row = (int)((blockIdx.x * 256 + threadIdx.x) >> 4);
    int lane = threadIdx.x & 15;
    if (row >= n_rows) return;
    int deg = cnt[row];
    deg = deg < CAP ? deg : CAP;
    const int2* bp = buckets + (size_t)row * CAP;
    float acc[8];
    #pragma unroll
    for (int i = 0; i < 8; ++i) acc[i] = 0.f;

    int k = 0;
    while (k < deg) {
        int nb = deg - k;            // remaining edges (uniform per 16-lane group)
        int2 p[8];
        #pragma unroll
        for (int j = 0; j < 8; ++j) p[j] = bp[k + j];  // within CAP row: safe
        uint4 v[8];
        #pragma unroll
        for (int j = 0; j < 8; ++j)
            if (j < nb)
                v[j] = *reinterpret_cast<const uint4*>(
                    xin_bf + (size_t)p[j].x * DIM + lane * 8);
        #pragma unroll
        for (int j = 0; j < 8; ++j)
            if (j < nb) accum8(v[j], __int_as_float(p[j].y), acc);
        k += 8;
    }

    float invc = 1.0f / fmaxf((float)deg, 1.0f);
    #pragma unroll
    for (int i = 0; i < 8; ++i) {
        acc[i] *= invc;
        acc[i] = acc[i] > 0.f ? acc[i] : NEG_SLOPE * acc[i];
    }
    size_t off = (size_t)row * DIM + lane * 8;
    if (MODE == 0) {
        uint4 pk;
        pk.x = (uint32)f2bf(acc[0]) | ((uint32)f2bf(acc[1]) << 16);
        pk.y = (uint32)f2bf(acc[2]) | ((uint32)f2bf(acc[3]) << 16);
        pk.z = (uint32)f2bf(acc[4]) | ((uint32)f2bf(acc[5]) << 16);
        pk.w = (uint32)f2bf(acc[6]) | ((uint32)f2bf(acc[7]) << 16);
        *reinterpret_cast<uint4*>(x1_bf + off) = pk;
    } else {
        uint4 xa = *reinterpret_cast<const uint4*>(x_bf + off);
        uint4 ya = *reinterpret_cast<const uint4*>(x1_bf + off);
        float4 o0, o1;
        o0.x = bf_lo(xa.x) + bf_lo(ya.x) + acc[0];
        o0.y = bf_hi(xa.x) + bf_hi(ya.x) + acc[1];
        o0.z = bf_lo(xa.y) + bf_lo(ya.y) + acc[2];
        o0.w = bf_hi(xa.y) + bf_hi(ya.y) + acc[3];
        o1.x = bf_lo(xa.z) + bf_lo(ya.z) + acc[4];
        o1.y = bf_hi(xa.z) + bf_hi(ya.z) + acc[5];
        o1.z = bf_lo(xa.w) + bf_lo(ya.w) + acc[6];
        o1.w = bf_hi(xa.w) + bf_hi(ya.w) + acc[7];
        float4* op = reinterpret_cast<float4*>(out + off);
        op[0] = o0;
        op[1] = o1;
    }
}

extern "C" void kernel_launch(void* const* d_in, const int* in_sizes, int n_in,
                              void* d_out, int out_size, void* d_ws, size_t ws_size,
                              hipStream_t stream) {
    const float* id_emb = (const float*)d_in[0];
    const int* ei = (const int*)d_in[1];
    const float* w = (const float*)d_in[2];
    float* out = (float*)d_out;

    const int N = in_sizes[0] / DIM;      // 100000
    const int E = in_sizes[1] / 2;        // 300000
    const size_t ND = (size_t)N * DIM;

    // workspace layout
    ushort16* x_bf = (ushort16*)d_ws;               // ND bf16        (25.6 MB)
    ushort16* x1_bf = x_bf + ND;                    // ND bf16        (25.6 MB)
    int* cnt = (int*)(x1_bf + ND);                  // N ints         (0.4 MB)
    int2* buckets = (int2*)(cnt + N);               // N*CAP int2     (25.6 MB)

    hipMemsetAsync(cnt, 0, (size_t)N * sizeof(int), stream);

    // fused: direct bucket fill (blocks first) + x = normalize(id_emb) -> x_bf
    {
        int fb = (2 * E + 255) / 256;
        int nb = (N * 8 + 255) / 256;
        norm_fill_kernel<<<fb + nb, 256, 0, stream>>>(
            id_emb, x_bf, ei, w, cnt, buckets, N, E, fb);
    }

    // conv1: gather x_bf -> x1_bf
    conv_kernel<0><<<(N * 16 + 255) / 256, 256, 0, stream>>>(
        x_bf, cnt, buckets, x1_bf, nullptr, nullptr, N);
    // conv2 + final fusion: out = x + x1 + leaky(mean)
    conv_kernel<1><<<(N * 16 + 255) / 256, 256, 0, stream>>>(
        x1_bf, cnt, buckets, x1_bf, x_bf, out, N);
}